// Round 6
// baseline (190.461 us; speedup 1.0000x reference)
//
#include <hip/hip_runtime.h>
#include <stdint.h>

#define NS 64     // N_msa (s)
#define NT 384    // N_tok (i, j)
#define CM 64     // c_m
#define CH 32     // c_h
#define CZ 128    // c_z

typedef __attribute__((ext_vector_type(8))) short bf16x8;
typedef __attribute__((ext_vector_type(16))) float f32x16;
typedef __attribute__((ext_vector_type(4))) float f32x4;

#define MFMA __builtin_amdgcn_mfma_f32_32x32x16_bf16

// round-to-nearest-even f32 -> bf16 bits
static __device__ __forceinline__ uint16_t f2bf(float f) {
  uint32_t u = __float_as_uint(f);
  u = (u + 0x7FFFu + ((u >> 16) & 1u)) >> 16;
  return (uint16_t)u;
}
static __device__ __forceinline__ uint32_t pack2(float lo, float hi) {
  return (uint32_t)f2bf(lo) | ((uint32_t)f2bf(hi) << 16);
}
// O-slab swizzle (byte = pair*256 + kl*2 within a 32 KB slab):
// bank bits 4..6 ^= (bits 8..10) ^ (bits 11..13). Involution; 16B-granule-preserving.
static __device__ __forceinline__ int swzO(int x) {
  return x ^ ((((x >> 8) ^ (x >> 11)) & 7) << 4);
}

// ---- merged prep: LN+proj -> AF2/BF; w_out -> W2 frag-major; inv_norm ------
// AF2: GEMM1 B-operand, slab-major: rb = (c>>2)*48 + (i>>3), r = (i&7)*4 + (c&3)
//   AF2[((rb*4+kk)*64 + lane)*8 + e] = a[s=kk*16+(lane>>5)*8+e][i][c], lane&31 = r
// BF : BF[((j*4+kk)*64 + lane)*8 + e] = b[s][j][d=lane&31]
// W2 : W2[((kk*4+zt)*64 + lane)*8 + e] = w_out[z=zt*32+(lane&31)][K=kk*16+(lane>>5)*8+e]
__global__ __launch_bounds__(256) void k_pre(
    const float* __restrict__ m, const float* __restrict__ mask,
    const float* __restrict__ lnw, const float* __restrict__ lnb,
    const float* __restrict__ w1, const float* __restrict__ w2,
    const float* __restrict__ wout,
    uint16_t* __restrict__ AF2, uint16_t* __restrict__ BF,
    uint16_t* __restrict__ W2, float* __restrict__ invn) {
  __shared__ float4 wsh4[2][1024];   // w1, w2 as float4 (32 KB)
  __shared__ float4 mn4[64 * 17];    // LN result, row pitch 17 float4 (68 f) = conflict-free
  const int b = blockIdx.x;
  const int tid = threadIdx.x;
  if (b < NT) {
    const int i = b;
    const int wv = tid >> 6, lane = tid & 63;
    for (int t = tid; t < 1024; t += 256) {
      wsh4[0][t] = ((const float4*)w1)[t];
      wsh4[1][t] = ((const float4*)w2)[t];
    }
    const float lw = lnw[lane], lb = lnb[lane];
    float* mnf = (float*)mn4;
    for (int s = wv; s < NS; s += 4) {
      float x = m[(s * NT + i) * CM + lane];
      float sum = x, sq = x * x;
#pragma unroll
      for (int off = 32; off; off >>= 1) {
        sum += __shfl_xor(sum, off);
        sq += __shfl_xor(sq, off);
      }
      float mu = sum * (1.f / 64.f);
      float var = sq * (1.f / 64.f) - mu * mu;
      float rs = 1.f / sqrtf(var + 1e-5f);
      mnf[s * 68 + lane] = (x - mu) * rs * lw + lb;
    }
    __syncthreads();
    const int s = lane;
    const int cb = tid >> 6;  // c = cb*8 + k
    float accA[8] = {0, 0, 0, 0, 0, 0, 0, 0};
    float accB[8] = {0, 0, 0, 0, 0, 0, 0, 0};
#pragma unroll
    for (int q = 0; q < 16; ++q) {
      float4 v = mn4[s * 17 + q];
#pragma unroll
      for (int k = 0; k < 8; ++k) {
        float4 wa = wsh4[0][(cb * 8 + k) * 16 + q];
        float4 wb = wsh4[1][(cb * 8 + k) * 16 + q];
        accA[k] = fmaf(v.x, wa.x, fmaf(v.y, wa.y, fmaf(v.z, wa.z, fmaf(v.w, wa.w, accA[k]))));
        accB[k] = fmaf(v.x, wb.x, fmaf(v.y, wb.y, fmaf(v.z, wb.z, fmaf(v.w, wb.w, accB[k]))));
      }
    }
    const float msk = mask[s * NT + i];
    const int kkq = s >> 4, hh = (s >> 3) & 1, e = s & 7;
    const size_t baseB = ((size_t)(i * 4 + kkq) * 64 + hh * 32) * 8 + e;
#pragma unroll
    for (int k = 0; k < 8; ++k) {
      int c = cb * 8 + k;
      BF[baseB + (size_t)c * 8] = f2bf(accB[k] * msk);
      int rb = (c >> 2) * 48 + (i >> 3);
      int r = (i & 7) * 4 + (c & 3);
      AF2[((size_t)(rb * 4 + kkq) * 64 + hh * 32 + r) * 8 + e] = f2bf(accA[k] * msk);
    }
  } else if (b < NT + 64) {
    const int g = (b - NT) * 256 + tid;  // 0..16383
    const int l = g & 63, zt = (g >> 6) & 3, kk = g >> 8;
    const float* src = wout + (zt * 32 + (l & 31)) * 1024 + kk * 16 + (l >> 5) * 8;
    uint16_t* dst = W2 + (size_t)g * 8;
#pragma unroll
    for (int e2 = 0; e2 < 8; ++e2) dst[e2] = f2bf(src[e2]);
  } else {
    const int t = (b - NT - 64) * 256 + tid;  // 0..147455
    const int i = t / NT, j = t - i * NT;
    float acc = 0.f;
#pragma unroll 8
    for (int s2 = 0; s2 < NS; ++s2) acc += mask[s2 * NT + i] * mask[s2 * NT + j];
    invn[t] = 1.f / (acc + 1e-3f);
  }
}

// ---- main: per block 16x8 (i,j) pairs (128), 8 c-slabs of K=128, fused GEMM1+GEMM2
// LDS (dynamic 66048): [0,32K) O buf0; [32K,64K) O buf1; reduce scratch reuses [0,64K);
//                      invn cache at [64K, 64K+512)
// waves: GEMM1 wave = jt (j-col, 2 i-halves); GEMM2 wave = (kxh, mp, zp): 2 m x 2 z accs,
//        kx-range split within each slab; final cross-kxh LDS reduce.
__global__ __launch_bounds__(512, 4) void k_main(
    const uint16_t* __restrict__ AF2, const uint16_t* __restrict__ BF,
    const uint16_t* __restrict__ W2, const float* __restrict__ b_out,
    const float* __restrict__ invn, float* __restrict__ out) {
  extern __shared__ char lds[];
  float* invLds = (float*)(lds + 65536);
  const int tid = threadIdx.x;
  const int wv = tid >> 6, l = tid & 63;
  const int lo5 = l & 31, hi = l >> 5;
  const int ib0 = blockIdx.x * 2;           // AF2 i-row-block base (2 per block)
  const int i0 = blockIdx.x * 16, j0 = blockIdx.y * 8;
  const int jt = wv;                                    // GEMM1 role
  const int kxh = wv >> 2, mp = (wv >> 1) & 1, zp = wv & 1;  // GEMM2 role

  // stage invn for this block's 128 pairs
  if (tid < 128) invLds[tid] = invn[(size_t)(i0 + (tid >> 3)) * NT + j0 + (tid & 7)];

  // preload BF fragments (reused by all 8 slabs)
  bf16x8 bfr[4];
  {
    const uint16_t* p = BF + (size_t)(j0 + jt) * 4 * 512 + (size_t)l * 8;
#pragma unroll
    for (int kk = 0; kk < 4; ++kk) bfr[kk] = *(const bf16x8*)(p + kk * 512);
  }

  f32x16 acc2[2][2];
#pragma unroll
  for (int mi = 0; mi < 2; ++mi)
#pragma unroll
    for (int zi = 0; zi < 2; ++zi) acc2[mi][zi] = (f32x16){};

  // O layout: byte = p*256 + kl*2; p = i_loc*8 + j; kl = c_loc*32 + d
  const int wcol = (lo5 >> 2) * 8 + jt;        // pair within ih-block for writes
  const int wbyte = (lo5 & 3) * 64 + hi * 8;   // kl part of write address
  const int p2base = mp * 2 * 32 * 256;        // GEMM2 m-tile base

  // ---- produce slab 0 into buf0
  {
    const uint16_t* Ap = AF2 + ((size_t)(0 * 48 + ib0) * 4) * 512 + (size_t)l * 8;
#pragma unroll
    for (int ih = 0; ih < 2; ++ih) {
      f32x16 a1 = (f32x16){};
#pragma unroll
      for (int kk = 0; kk < 4; ++kk) {
        bf16x8 af = *(const bf16x8*)(Ap + (ih * 4 + kk) * 512);
        a1 = MFMA(bfr[kk], af, a1, 0, 0, 0);
      }
      const int base = (ih * 64 + wcol) * 256 + wbyte;
#pragma unroll
      for (int g = 0; g < 4; ++g) {
        uint64_t v = (uint64_t)pack2(a1[4 * g + 0], a1[4 * g + 1]) |
                     ((uint64_t)pack2(a1[4 * g + 2], a1[4 * g + 3]) << 32);
        *(uint64_t*)(lds + swzO(base + g * 16)) = v;
      }
    }
  }
  __syncthreads();

  for (int cbk = 1; cbk <= 8; ++cbk) {
    // ---- produce slab cbk into buf[cbk&1] (skipped on last iteration)
    if (cbk < 8) {
      char* ldsO = lds + (cbk & 1) * 32768;
      const uint16_t* Ap = AF2 + ((size_t)(cbk * 48 + ib0) * 4) * 512 + (size_t)l * 8;
#pragma unroll
      for (int ih = 0; ih < 2; ++ih) {
        f32x16 a1 = (f32x16){};
#pragma unroll
        for (int kk = 0; kk < 4; ++kk) {
          bf16x8 af = *(const bf16x8*)(Ap + (ih * 4 + kk) * 512);
          a1 = MFMA(bfr[kk], af, a1, 0, 0, 0);
        }
        const int base = (ih * 64 + wcol) * 256 + wbyte;
#pragma unroll
        for (int g = 0; g < 4; ++g) {
          uint64_t v = (uint64_t)pack2(a1[4 * g + 0], a1[4 * g + 1]) |
                       ((uint64_t)pack2(a1[4 * g + 2], a1[4 * g + 3]) << 32);
          *(uint64_t*)(ldsO + swzO(base + g * 16)) = v;
        }
      }
    }

    // ---- consume slab t = cbk-1 from buf[t&1]: kx range [kxh*4, kxh*4+4)
    {
      const int t = cbk - 1;
      char* ldsO = lds + (t & 1) * 32768;
      const uint16_t* Wp = W2 + ((size_t)((t * 8 + kxh * 4) * 4 + zp * 2) * 64 + l) * 8;
#pragma unroll
      for (int kq = 0; kq < 4; ++kq) {
        const int kx = kxh * 4 + kq;
        bf16x8 of[2], wf[2];
#pragma unroll
        for (int mi = 0; mi < 2; ++mi)
          of[mi] = *(const bf16x8*)(ldsO + swzO(p2base + mi * 8192 + lo5 * 256 + kx * 32 + hi * 16));
#pragma unroll
        for (int zi = 0; zi < 2; ++zi)
          wf[zi] = *(const bf16x8*)(Wp + (size_t)(kq * 4 + zi) * 512);
#pragma unroll
        for (int mi = 0; mi < 2; ++mi)
#pragma unroll
          for (int zi = 0; zi < 2; ++zi)
            acc2[mi][zi] = MFMA(of[mi], wf[zi], acc2[mi][zi], 0, 0, 0);
      }
    }
    if (cbk < 8) __syncthreads();
  }

  // ---- cross-kxh reduce: protect scratch (reuses O buffers) from in-flight reads
  __syncthreads();
  const int sidx = mp * 2 + zp;
  if (kxh == 1) {
#pragma unroll
    for (int mi = 0; mi < 2; ++mi)
#pragma unroll
      for (int zi = 0; zi < 2; ++zi)
#pragma unroll
        for (int g = 0; g < 4; ++g) {
          f32x4 v = {acc2[mi][zi][4 * g + 0], acc2[mi][zi][4 * g + 1],
                     acc2[mi][zi][4 * g + 2], acc2[mi][zi][4 * g + 3]};
          *(f32x4*)(lds + sidx * 16384 + ((mi * 2 + zi) * 4 + g) * 1024 + l * 16) = v;
        }
  }
  __syncthreads();
  if (kxh == 0) {
#pragma unroll
    for (int mi = 0; mi < 2; ++mi)
#pragma unroll
      for (int zi = 0; zi < 2; ++zi)
#pragma unroll
        for (int g = 0; g < 4; ++g) {
          f32x4 v = *(const f32x4*)(lds + sidx * 16384 + ((mi * 2 + zi) * 4 + g) * 1024 + l * 16);
#pragma unroll
          for (int jj = 0; jj < 4; ++jj) acc2[mi][zi][4 * g + jj] += v[jj];
        }
    // ---- epilogue
    const float bo0 = b_out[(zp * 2) * 32 + lo5];
    const float bo1 = b_out[(zp * 2 + 1) * 32 + lo5];
#pragma unroll
    for (int mi = 0; mi < 2; ++mi) {
      const int mt = mp * 2 + mi;
#pragma unroll
      for (int e = 0; e < 16; ++e) {
        const int prow = mt * 32 + (e & 3) + 8 * (e >> 2) + 4 * hi;  // pair = i_loc*8 + j
        const float inv = invLds[prow];
        const size_t n = (size_t)(i0 + (prow >> 3)) * NT + j0 + (prow & 7);
        out[n * CZ + zp * 64 + lo5] = (acc2[mi][0][e] + bo0) * inv;
        out[n * CZ + zp * 64 + 32 + lo5] = (acc2[mi][1][e] + bo1) * inv;
      }
    }
  }
}

extern "C" void kernel_launch(void* const* d_in, const int* in_sizes, int n_in,
                              void* d_out, int out_size, void* d_ws, size_t ws_size,
                              hipStream_t stream) {
  const float* m    = (const float*)d_in[0];
  const float* mask = (const float*)d_in[1];
  const float* lnw  = (const float*)d_in[2];
  const float* lnb  = (const float*)d_in[3];
  const float* w1   = (const float*)d_in[4];
  const float* w2   = (const float*)d_in[5];
  const float* wout = (const float*)d_in[6];
  const float* bout = (const float*)d_in[7];
  float* out = (float*)d_out;

  char* ws = (char*)d_ws;
  uint16_t* AF2 = (uint16_t*)ws;                        // 1.5 MB
  uint16_t* BF  = (uint16_t*)(ws + 1572864);            // 1.5 MB
  uint16_t* W2  = (uint16_t*)(ws + 3145728);            // 256 KB
  float* invn   = (float*)(ws + 3407872);               // 576 KB

  k_pre<<<1024, 256, 0, stream>>>(m, mask, lnw, lnb, w1, w2, wout, AF2, BF, W2, invn);

  (void)hipFuncSetAttribute(reinterpret_cast<const void*>(k_main),
                            hipFuncAttributeMaxDynamicSharedMemorySize, 66048);
  k_main<<<dim3(NT / 16, NT / 8), 512, 66048, stream>>>(AF2, BF, W2, bout, invn, out);
}